// Round 13
// baseline (26.087 us; speedup 1.0000x reference)
//
#include <hip/hip_runtime.h>
#include <stdint.h>

// Problem constants: B,D,K,CI,CO,L,NB,P,S = 4,32,8,2,2,4096,15,7,8
constexpr int Bc  = 4;
constexpr int Dc  = 32;
constexpr int Kc  = 8;
constexpr int CIc = 2;
constexpr int COc = 2;
constexpr int Lc  = 4096;
constexpr int NBc = 15;
constexpr int Sc  = 8;

constexpr int NTHREADS = 256;
constexpr int JT       = 4;                  // outputs per thread per co per tile
constexpr int TILE     = NTHREADS * JT;      // 1024
constexpr int NTILES   = Lc / TILE;          // 4 tiles = whole row per block
constexpr int WELEMS   = COc * CIc * Sc * NBc;  // 480

typedef float f32x4 __attribute__((ext_vector_type(4)));
typedef const __attribute__((address_space(1))) float* gas1_t;  // global
typedef __attribute__((address_space(3))) float* las3_t;        // LDS

// seg(l) = min(l/499, 7)
__device__ __forceinline__ int seg_of(int l) {
    int s = l / 499;
    return s > 7 ? 7 : s;
}

__global__ __launch_bounds__(NTHREADS) void cde_bcr_kernel(
    const float* __restrict__ x,     // [B][D][K][CI][L]
    const float* __restrict__ w,     // [D][K][CO][CI][S][1][NB]
    const float* __restrict__ bias,  // [D][K][CO][S][1]
    float* __restrict__ out)         // [B][D][K][CO][L]
{
    // whole x row staged: xs[i][8 + l] = x[i][l]; halos [0,8) and [8+Lc,16+Lc) zeroed
    __shared__ __align__(16) float xs[CIc][Lc + 16];          // 32.9 KB -> 4 blocks/CU
    __shared__ __align__(16) float wl[COc * CIc * Sc][16];    // 2 KB
    __shared__ float bl[COc * Sc];

    const int tid  = threadIdx.x;
    const int lane = tid & 63;
    const int wid  = tid >> 6;
    const int bdk  = blockIdx.x;             // ((b*D + d)*K + k), 1024 blocks
    const int dk   = bdk % (Dc * Kc);

    // ---- fire-and-forget: whole row direct HBM->LDS, zero VGPR cost (m97 width=16) ----
    // LDS dest wave-uniform base + lane*16 (m104); all byte offsets 16B-aligned.
    const float* xrow = x + (size_t)bdk * CIc * Lc;
#pragma unroll
    for (int i = 0; i < CIc; ++i) {
#pragma unroll
        for (int q = 0; q < 4; ++q) {        // 4 sweeps x 1024 floats per ci
            const float* g = xrow + (size_t)i * Lc + q * 1024 + wid * 256 + lane * 4;
            float* lp = &xs[i][8 + q * 1024 + wid * 256];   // wave-uniform base
            __builtin_amdgcn_global_load_lds((gas1_t)g, (las3_t)lp, 16, 0, 0);
        }
    }

    // ---- weights + bias (regular staging, overlaps DMA) ----
    for (int t = tid; t < WELEMS; t += NTHREADS)
        wl[t / NBc][t % NBc] = w[(size_t)dk * WELEMS + t];
    if (tid < COc * Sc)
        bl[tid] = bias[(size_t)dk * (COc * Sc) + tid];

    // ---- zero halos (row ends pad with 0) ----
    if (tid < 2 * 16) {
        int i = tid >> 4, e = tid & 15;
        int idx = (e < 8) ? e : (Lc + e);    // [0,8) and [Lc+8, Lc+16)
        xs[i][idx] = 0.0f;
    }

    __syncthreads();   // drains DMA + LDS writes; blocks release staggered grid-wide

#pragma unroll
    for (int t = 0; t < NTILES; ++t) {
        const int gl0 = t * TILE + tid * JT;
        const int s0  = seg_of(gl0);
        const int s3  = seg_of(gl0 + JT - 1);

        // windows: xa_i[m] = x[i][gl0-8+m] = xs[i][gl0+m], m in [0,20)
        // ds_read_b128 at 16B lane stride: contiguous 1KB/wave -> conflict-free
        float xa0[20], xa1[20];
#pragma unroll
        for (int m = 0; m < 5; ++m) {
            *(f32x4*)&xa0[4 * m] = *(const f32x4*)&xs[0][gl0 + 4 * m];
            *(f32x4*)&xa1[4 * m] = *(const f32x4*)&xs[1][gl0 + 4 * m];
        }

        float acc[COc][JT];
#pragma unroll
        for (int o = 0; o < COc; ++o)
#pragma unroll
            for (int j = 0; j < JT; ++j)
                acc[o][j] = bl[o * Sc + s0];

#pragma unroll
        for (int i = 0; i < CIc; ++i) {
            float wa[16], wb[16];
#pragma unroll
            for (int m = 0; m < 4; ++m) {
                *(f32x4*)&wa[4 * m] = *(const f32x4*)&wl[(0 * CIc + i) * Sc + s0][4 * m];
                *(f32x4*)&wb[4 * m] = *(const f32x4*)&wl[(1 * CIc + i) * Sc + s0][4 * m];
            }
#pragma unroll
            for (int f = 0; f < NBc; ++f) {
#pragma unroll
                for (int j = 0; j < JT; ++j) {
                    float xv = (i == 0) ? xa0[j + f + 1] : xa1[j + f + 1];
                    acc[0][j] = fmaf(wa[f], xv, acc[0][j]);
                    acc[1][j] = fmaf(wb[f], xv, acc[1][j]);
                }
            }
        }

        // fixup: segment-boundary threads, all register indices static
        if (s3 != s0) {
            const int jstart = 499 * s3 - gl0;   // in [1, JT-1]
            const float b0 = bl[0 * Sc + s3];
            const float b1 = bl[1 * Sc + s3];
#pragma unroll
            for (int j = 0; j < JT; ++j) {
                if (j >= jstart) {
                    float a0 = b0, a1 = b1;
#pragma unroll
                    for (int i = 0; i < CIc; ++i) {
#pragma unroll
                        for (int f = 0; f < NBc; ++f) {
                            float xv = (i == 0) ? xa0[j + f + 1] : xa1[j + f + 1];
                            a0 = fmaf(wl[(0 * CIc + i) * Sc + s3][f], xv, a0);
                            a1 = fmaf(wl[(1 * CIc + i) * Sc + s3][f], xv, a1);
                        }
                    }
                    acc[0][j] = a0;
                    acc[1][j] = a1;
                }
            }
        }

        // store: PLAIN cached dwordx4 (not nontemporal): out stays dirty in L2/L3
        // (66 MB working set << 256 MB Infinity Cache -> steady-state replays avoid HBM)
        float* ob = out + (size_t)bdk * COc * Lc + gl0;
        f32x4 v0 = { acc[0][0], acc[0][1], acc[0][2], acc[0][3] };
        f32x4 v1 = { acc[1][0], acc[1][1], acc[1][2], acc[1][3] };
        *(f32x4*)(ob)      = v0;
        *(f32x4*)(ob + Lc) = v1;
    }
}

extern "C" void kernel_launch(void* const* d_in, const int* in_sizes, int n_in,
                              void* d_out, int out_size, void* d_ws, size_t ws_size,
                              hipStream_t stream) {
    const float* x    = (const float*)d_in[0];
    const float* w    = (const float*)d_in[1];
    const float* bias = (const float*)d_in[2];
    float* out        = (float*)d_out;

    // 1024 blocks = full-grid resident (4 blocks/CU by LDS), staggered barrier release
    cde_bcr_kernel<<<dim3(Bc * Dc * Kc), NTHREADS, 0, stream>>>(x, w, bias, out);
}

// Round 14
// 22.596 us; speedup vs baseline: 1.1545x; 1.1545x over previous
//
#include <hip/hip_runtime.h>
#include <stdint.h>

// Problem constants: B,D,K,CI,CO,L,NB,P,S = 4,32,8,2,2,4096,15,7,8
constexpr int Bc  = 4;
constexpr int Dc  = 32;
constexpr int Kc  = 8;
constexpr int CIc = 2;
constexpr int COc = 2;
constexpr int Lc  = 4096;
constexpr int NBc = 15;
constexpr int Sc  = 8;

constexpr int NTHREADS = 256;
constexpr int JT       = 8;                  // outputs per thread per co per tile
constexpr int TILE     = NTHREADS * JT;      // 2048
constexpr int NTILES   = Lc / TILE;          // 2 tiles = whole row per block
constexpr int WELEMS   = COc * CIc * Sc * NBc;  // 480
constexpr int WIN      = JT + 16;            // 24-float window per ci

typedef float f32x4 __attribute__((ext_vector_type(4)));
typedef const __attribute__((address_space(1))) float* gas1_t;  // global
typedef __attribute__((address_space(3))) float* las3_t;        // LDS

// seg(l) = min(l/499, 7)
__device__ __forceinline__ int seg_of(int l) {
    int s = l / 499;
    return s > 7 ? 7 : s;
}

__global__ __launch_bounds__(NTHREADS) void cde_bcr_kernel(
    const float* __restrict__ x,     // [B][D][K][CI][L]
    const float* __restrict__ w,     // [D][K][CO][CI][S][1][NB]
    const float* __restrict__ bias,  // [D][K][CO][S][1]
    float* __restrict__ out)         // [B][D][K][CO][L]
{
    // whole x row staged: xs[i][8 + l] = x[i][l]; halos [0,8) and [8+Lc,16+Lc) zeroed
    __shared__ __align__(16) float xs[CIc][Lc + 16];          // 32.9 KB -> 4 blocks/CU
    __shared__ __align__(16) float wl[COc * CIc * Sc][16];    // 2 KB
    __shared__ float bl[COc * Sc];

    const int tid  = threadIdx.x;
    const int lane = tid & 63;
    const int wid  = tid >> 6;
    const int bdk  = blockIdx.x;             // ((b*D + d)*K + k), 1024 blocks
    const int dk   = bdk % (Dc * Kc);

    // ---- fire-and-forget: whole row direct HBM->LDS, zero VGPR cost (m97 width=16) ----
    // LDS dest wave-uniform base + lane*16 (m104); all byte offsets 16B-aligned.
    const float* xrow = x + (size_t)bdk * CIc * Lc;
#pragma unroll
    for (int i = 0; i < CIc; ++i) {
#pragma unroll
        for (int q = 0; q < 4; ++q) {        // 4 sweeps x 1024 floats per ci
            const float* g = xrow + (size_t)i * Lc + q * 1024 + wid * 256 + lane * 4;
            float* lp = &xs[i][8 + q * 1024 + wid * 256];   // wave-uniform base
            __builtin_amdgcn_global_load_lds((gas1_t)g, (las3_t)lp, 16, 0, 0);
        }
    }

    // ---- weights + bias (regular staging, overlaps DMA) ----
    for (int t = tid; t < WELEMS; t += NTHREADS)
        wl[t / NBc][t % NBc] = w[(size_t)dk * WELEMS + t];
    if (tid < COc * Sc)
        bl[tid] = bias[(size_t)dk * (COc * Sc) + tid];

    // ---- zero halos (row ends pad with 0) ----
    if (tid < 2 * 16) {
        int i = tid >> 4, e = tid & 15;
        int idx = (e < 8) ? e : (Lc + e);    // [0,8) and [Lc+8, Lc+16)
        xs[i][idx] = 0.0f;
    }

    __syncthreads();   // drains DMA + LDS writes; blocks release staggered grid-wide

#pragma unroll
    for (int t = 0; t < NTILES; ++t) {
        const int gl0 = t * TILE + tid * JT;
        const int s0  = seg_of(gl0);
        const int s7  = seg_of(gl0 + JT - 1);

        // windows: xa_i[m] = x[i][gl0-8+m] = xs[i][gl0+m], m in [0,24): 6 b128 per ci
        float xa0[WIN], xa1[WIN];
#pragma unroll
        for (int m = 0; m < WIN / 4; ++m) {
            *(f32x4*)&xa0[4 * m] = *(const f32x4*)&xs[0][gl0 + 4 * m];
            *(f32x4*)&xa1[4 * m] = *(const f32x4*)&xs[1][gl0 + 4 * m];
        }

        float acc[COc][JT];
#pragma unroll
        for (int o = 0; o < COc; ++o)
#pragma unroll
            for (int j = 0; j < JT; ++j)
                acc[o][j] = bl[o * Sc + s0];

#pragma unroll
        for (int i = 0; i < CIc; ++i) {
            float wa[16], wb[16];
#pragma unroll
            for (int m = 0; m < 4; ++m) {
                *(f32x4*)&wa[4 * m] = *(const f32x4*)&wl[(0 * CIc + i) * Sc + s0][4 * m];
                *(f32x4*)&wb[4 * m] = *(const f32x4*)&wl[(1 * CIc + i) * Sc + s0][4 * m];
            }
#pragma unroll
            for (int f = 0; f < NBc; ++f) {
#pragma unroll
                for (int j = 0; j < JT; ++j) {
                    float xv = (i == 0) ? xa0[j + f + 1] : xa1[j + f + 1];
                    acc[0][j] = fmaf(wa[f], xv, acc[0][j]);
                    acc[1][j] = fmaf(wb[f], xv, acc[1][j]);
                }
            }
        }

        // fixup: segment-boundary threads (<=7 per bdk row), all register indices static
        if (s7 != s0) {
            const int jstart = 499 * s7 - gl0;   // in [1, JT-1]
            const float b0 = bl[0 * Sc + s7];
            const float b1 = bl[1 * Sc + s7];
#pragma unroll
            for (int j = 0; j < JT; ++j) {
                if (j >= jstart) {
                    float a0 = b0, a1 = b1;
#pragma unroll
                    for (int i = 0; i < CIc; ++i) {
#pragma unroll
                        for (int f = 0; f < NBc; ++f) {
                            float xv = (i == 0) ? xa0[j + f + 1] : xa1[j + f + 1];
                            a0 = fmaf(wl[(0 * CIc + i) * Sc + s7][f], xv, a0);
                            a1 = fmaf(wl[(1 * CIc + i) * Sc + s7][f], xv, a1);
                        }
                    }
                    acc[0][j] = a0;
                    acc[1][j] = a1;
                }
            }
        }

        // store: 4 nontemporal dwordx4 per tile (NT proven right: r13 plain stores -7.3us)
        float* ob = out + (size_t)bdk * COc * Lc + gl0;
#pragma unroll
        for (int o = 0; o < COc; ++o) {
            f32x4 v0 = { acc[o][0], acc[o][1], acc[o][2], acc[o][3] };
            f32x4 v1 = { acc[o][4], acc[o][5], acc[o][6], acc[o][7] };
            __builtin_nontemporal_store(v0, (f32x4*)(ob + (size_t)o * Lc));
            __builtin_nontemporal_store(v1, (f32x4*)(ob + (size_t)o * Lc + 4));
        }
    }
}

extern "C" void kernel_launch(void* const* d_in, const int* in_sizes, int n_in,
                              void* d_out, int out_size, void* d_ws, size_t ws_size,
                              hipStream_t stream) {
    const float* x    = (const float*)d_in[0];
    const float* w    = (const float*)d_in[1];
    const float* bias = (const float*)d_in[2];
    float* out        = (float*)d_out;

    // 1024 blocks = full-grid resident (4 blocks/CU by LDS), staggered barrier release
    cde_bcr_kernel<<<dim3(Bc * Dc * Kc), NTHREADS, 0, stream>>>(x, w, bias, out);
}

// Round 15
// 20.944 us; speedup vs baseline: 1.2456x; 1.0789x over previous
//
#include <hip/hip_runtime.h>
#include <stdint.h>

// Problem constants: B,D,K,CI,CO,L,NB,P,S = 4,32,8,2,2,4096,15,7,8
constexpr int Bc  = 4;
constexpr int Dc  = 32;
constexpr int Kc  = 8;
constexpr int CIc = 2;
constexpr int COc = 2;
constexpr int Lc  = 4096;
constexpr int NBc = 15;
constexpr int Sc  = 8;

constexpr int NTHREADS = 256;
constexpr int JT       = 4;                   // outputs per thread per co per tile
constexpr int CHUNK    = 1024;                // floats per wave-chunk (= Lc/4 waves)
constexpr int WELEMS   = COc * CIc * Sc * NBc;   // 480

typedef float f32x4 __attribute__((ext_vector_type(4)));
typedef const __attribute__((address_space(1))) float* gas1_t;  // global
typedef __attribute__((address_space(3))) float* las3_t;        // LDS

// seg(l) = min(l/499, 7)
__device__ __forceinline__ int seg_of(int l) {
    int s = l / 499;
    return s > 7 ? 7 : s;
}

__global__ __launch_bounds__(NTHREADS) void cde_bcr_kernel(
    const float* __restrict__ x,     // [B][D][K][CI][L]
    const float* __restrict__ w,     // [D][K][CO][CI][S][1][NB]
    const float* __restrict__ bias,  // [D][K][CO][S][1]
    float* __restrict__ out)         // [B][D][K][CO][L]
{
    // xs[i][8 + l] = x[i][l]; wave wv owns l in [wv*1024, wv*1024+1024).
    // NO BARRIERS: each wave waits only on its OWN DMAs (vmcnt is per-wave).
    __shared__ __align__(16) float xs[CIc][Lc + 16];          // 32.9 KB -> 4 blocks/CU
    __shared__ __align__(16) float wl[COc * CIc * Sc][16];    // 2 KB
    __shared__ float bl[COc * Sc];

    const int tid  = threadIdx.x;
    const int lane = tid & 63;
    const int wv   = tid >> 6;               // wave 0..3
    const int bdk  = blockIdx.x;             // ((b*D + d)*K + k), 1024 blocks
    const int dk   = bdk % (Dc * Kc);

    const float* xrow = x + (size_t)bdk * CIc * Lc;

    // ---- 1. per-wave fire-and-forget DMA of OWN chunk (8 x gload_lds_dwordx4) ----
    // LDS dest wave-uniform base + lane*16 (m104); offsets 16B-aligned.
#pragma unroll
    for (int i = 0; i < CIc; ++i) {
#pragma unroll
        for (int q = 0; q < CHUNK / 256; ++q) {
            const float* g = xrow + (size_t)i * Lc + wv * CHUNK + q * 256 + lane * 4;
            float* lp = &xs[i][8 + wv * CHUNK + q * 256];   // wave-uniform base
            __builtin_amdgcn_global_load_lds((gas1_t)g, (las3_t)lp, 16, 0, 0);
        }
    }

    // ---- 2. per-wave REDUNDANT weight+bias staging (identical values; benign race).
    // Overlaps the DMA latency. Each wave is then self-sufficient after its own lgkmcnt.
    for (int t = lane; t < WELEMS; t += 64)
        wl[t / NBc][t % NBc] = w[(size_t)dk * WELEMS + t];
    if (lane < COc * Sc)
        bl[lane] = bias[(size_t)dk * (COc * Sc) + lane];

    // ---- 3. per-wave wait on own DMAs + own LDS writes. No s_barrier anywhere. ----
    asm volatile("s_waitcnt vmcnt(0) lgkmcnt(0)" ::: "memory");
    __builtin_amdgcn_sched_barrier(0);

    // ---- 4. compute: 4 tiles of 256 outputs per wave, all within own chunk ----
#pragma unroll
    for (int t = 0; t < 4; ++t) {
        const int low = t * 256 + lane * JT;   // offset within wave chunk
        const int gl0 = wv * CHUNK + low;      // row-local l
        const int s0  = seg_of(gl0);
        const int s3  = seg_of(gl0 + JT - 1);

        // window xa_i[m] = x[i][gl0-8+m], m in [0,20)
        float xa0[20], xa1[20];
        if (low >= 8 && low <= CHUNK - 12) {
            // interior: LDS, 5 x ds_read_b128 per ci, 16B lane stride -> conflict-free
#pragma unroll
            for (int m = 0; m < 5; ++m) {
                *(f32x4*)&xa0[4 * m] = *(const f32x4*)&xs[0][gl0 + 4 * m];
                *(f32x4*)&xa1[4 * m] = *(const f32x4*)&xs[1][gl0 + 4 * m];
            }
        } else {
            // chunk-edge threads (2 per wave at t=0, 2 at t=3): global, bounds-checked.
            // Also covers row ends (l<0 / l>=Lc -> 0), so no zero-halo staging needed.
#pragma unroll
            for (int m = 0; m < 20; ++m) {
                int l = gl0 - 8 + m;
                bool ok = (l >= 0 && l < Lc);
                xa0[m] = ok ? xrow[l] : 0.0f;
                xa1[m] = ok ? xrow[Lc + l] : 0.0f;
            }
        }

        float acc[COc][JT];
#pragma unroll
        for (int o = 0; o < COc; ++o)
#pragma unroll
            for (int j = 0; j < JT; ++j)
                acc[o][j] = bl[o * Sc + s0];

#pragma unroll
        for (int i = 0; i < CIc; ++i) {
            float wa[16], wb[16];
#pragma unroll
            for (int m = 0; m < 4; ++m) {
                *(f32x4*)&wa[4 * m] = *(const f32x4*)&wl[(0 * CIc + i) * Sc + s0][4 * m];
                *(f32x4*)&wb[4 * m] = *(const f32x4*)&wl[(1 * CIc + i) * Sc + s0][4 * m];
            }
#pragma unroll
            for (int f = 0; f < NBc; ++f) {
#pragma unroll
                for (int j = 0; j < JT; ++j) {
                    float xv = (i == 0) ? xa0[j + f + 1] : xa1[j + f + 1];
                    acc[0][j] = fmaf(wa[f], xv, acc[0][j]);
                    acc[1][j] = fmaf(wb[f], xv, acc[1][j]);
                }
            }
        }

        // fixup: segment-boundary threads (<=7 per bdk row), all register indices static
        if (s3 != s0) {
            const int jstart = 499 * s3 - gl0;   // in [1, JT-1]
            const float b0 = bl[0 * Sc + s3];
            const float b1 = bl[1 * Sc + s3];
#pragma unroll
            for (int j = 0; j < JT; ++j) {
                if (j >= jstart) {
                    float a0 = b0, a1 = b1;
#pragma unroll
                    for (int i = 0; i < CIc; ++i) {
#pragma unroll
                        for (int f = 0; f < NBc; ++f) {
                            float xv = (i == 0) ? xa0[j + f + 1] : xa1[j + f + 1];
                            a0 = fmaf(wl[(0 * CIc + i) * Sc + s3][f], xv, a0);
                            a1 = fmaf(wl[(1 * CIc + i) * Sc + s3][f], xv, a1);
                        }
                    }
                    acc[0][j] = a0;
                    acc[1][j] = a1;
                }
            }
        }

        // store: 2 nontemporal dwordx4 (NT proven right: r13 plain stores -7.3us)
        float* ob = out + (size_t)bdk * COc * Lc + gl0;
        f32x4 v0 = { acc[0][0], acc[0][1], acc[0][2], acc[0][3] };
        f32x4 v1 = { acc[1][0], acc[1][1], acc[1][2], acc[1][3] };
        __builtin_nontemporal_store(v0, (f32x4*)(ob));
        __builtin_nontemporal_store(v1, (f32x4*)(ob + Lc));
    }
}

extern "C" void kernel_launch(void* const* d_in, const int* in_sizes, int n_in,
                              void* d_out, int out_size, void* d_ws, size_t ws_size,
                              hipStream_t stream) {
    const float* x    = (const float*)d_in[0];
    const float* w    = (const float*)d_in[1];
    const float* bias = (const float*)d_in[2];
    float* out        = (float*)d_out;

    // 1024 blocks, 4 independent waves each: no intra-block sync at all
    cde_bcr_kernel<<<dim3(Bc * Dc * Kc), NTHREADS, 0, stream>>>(x, w, bias, out);
}

// Round 16
// 19.363 us; speedup vs baseline: 1.3472x; 1.0816x over previous
//
#include <hip/hip_runtime.h>
#include <stdint.h>

// Problem constants: B,D,K,CI,CO,L,NB,P,S = 4,32,8,2,2,4096,15,7,8
constexpr int Bc  = 4;
constexpr int Dc  = 32;
constexpr int Kc  = 8;
constexpr int CIc = 2;
constexpr int COc = 2;
constexpr int Lc  = 4096;
constexpr int NBc = 15;
constexpr int Sc  = 8;

constexpr int NTHREADS = 512;                 // 8 waves
constexpr int JT       = 4;                   // outputs per thread per co per tile
constexpr int TILE     = NTHREADS * JT;       // 2048
constexpr int NTILES   = Lc / TILE;           // 2
constexpr int NROWS    = Bc * Dc * Kc;        // 1024
constexpr int NBLK     = NROWS / 2;           // 512 blocks, row pair (i, i+512): same dk
constexpr int WELEMS   = COc * CIc * Sc * NBc;   // 480

typedef float f32x4 __attribute__((ext_vector_type(4)));
typedef const __attribute__((address_space(1))) float* gas1_t;  // global
typedef __attribute__((address_space(3))) float* las3_t;        // LDS

// seg(l) = min(l/499, 7)
__device__ __forceinline__ int seg_of(int l) {
    int s = l / 499;
    return s > 7 ? 7 : s;
}

__global__ __launch_bounds__(NTHREADS) void cde_bcr_kernel(
    const float* __restrict__ x,     // [B][D][K][CI][L]
    const float* __restrict__ w,     // [D][K][CO][CI][S][1][NB]
    const float* __restrict__ bias,  // [D][K][CO][S][1]
    float* __restrict__ out)         // [B][D][K][CO][L]
{
    // double-buffered whole rows: xs[bf][i][8+l] = x_row[i][l]
    __shared__ __align__(16) float xs[2][CIc][Lc + 16];       // 65.8 KB -> 2 blocks/CU
    __shared__ __align__(16) float wl[COc * CIc * Sc][16];    // 2 KB
    __shared__ float bl[COc * Sc];

    const int tid  = threadIdx.x;
    const int lane = tid & 63;
    const int wv   = tid >> 6;               // wave 0..7
    const int r0   = blockIdx.x;             // first row
    const int r1   = blockIdx.x + NBLK;      // second row, same dk = r0 % 256
    const int dk   = r0 % (Dc * Kc);

    // ---- 1. weights + bias + halo zeros FIRST (their compiler-inserted vmcnt
    //         waits must not drain the DMA queue, so no DMAs are in flight yet) ----
    if (tid < WELEMS)
        wl[tid / NBc][tid % NBc] = w[(size_t)dk * WELEMS + tid];
    if (tid < COc * Sc)
        bl[tid] = bias[(size_t)dk * (COc * Sc) + tid];
    if (tid < 2 * CIc * 16) {                // zero halos of both buffers
        int bf = tid >> 5, i = (tid >> 4) & 1, e = tid & 15;
        int idx = (e < 8) ? e : (Lc + e);    // [0,8) and [Lc+8, Lc+16)
        xs[bf][i][idx] = 0.0f;
    }
    __builtin_amdgcn_sched_barrier(0);

    // ---- 2. fire-and-forget DMA: BOTH rows up front (4 gload/wave/row).
    // Row-1 reads stream into LDS while row-0 computes -> HBM never idles.
    // LDS dest wave-uniform base + lane*16 (m104); offsets 16B-aligned.
    const float* xr0 = x + (size_t)r0 * CIc * Lc;
    const float* xr1 = x + (size_t)r1 * CIc * Lc;
#pragma unroll
    for (int i = 0; i < CIc; ++i)
#pragma unroll
        for (int q = 0; q < 2; ++q) {        // wave owns floats [wv*512, wv*512+512)
            const float* g = xr0 + (size_t)i * Lc + wv * 512 + q * 256 + lane * 4;
            __builtin_amdgcn_global_load_lds((gas1_t)g,
                (las3_t)&xs[0][i][8 + wv * 512 + q * 256], 16, 0, 0);
        }
#pragma unroll
    for (int i = 0; i < CIc; ++i)
#pragma unroll
        for (int q = 0; q < 2; ++q) {
            const float* g = xr1 + (size_t)i * Lc + wv * 512 + q * 256 + lane * 4;
            __builtin_amdgcn_global_load_lds((gas1_t)g,
                (las3_t)&xs[1][i][8 + wv * 512 + q * 256], 16, 0, 0);
        }
    __builtin_amdgcn_sched_barrier(0);

#pragma unroll
    for (int r = 0; r < 2; ++r) {
        // counted wait: own row-r DMAs done; later ops (other row's DMAs at r=0,
        // NT stores at r=1) may remain outstanding (vmcnt retires in issue order)
        asm volatile("s_waitcnt vmcnt(4) lgkmcnt(0)" ::: "memory");
        __builtin_amdgcn_s_barrier();
        __builtin_amdgcn_sched_barrier(0);

        const int row = (r == 0) ? r0 : r1;
        const float (*xsb)[Lc + 16] = xs[r];
        float* obase = out + (size_t)row * COc * Lc;

#pragma unroll
        for (int t = 0; t < NTILES; ++t) {
            const int gl0 = t * TILE + tid * JT;
            const int s0  = seg_of(gl0);
            const int s3  = seg_of(gl0 + JT - 1);

            // windows: xa_i[m] = row[i][gl0-8+m] = xsb[i][gl0+m], m in [0,20)
            // ds_read_b128, 16B lane stride -> conflict-free
            float xa0[20], xa1[20];
#pragma unroll
            for (int m = 0; m < 5; ++m) {
                *(f32x4*)&xa0[4 * m] = *(const f32x4*)&xsb[0][gl0 + 4 * m];
                *(f32x4*)&xa1[4 * m] = *(const f32x4*)&xsb[1][gl0 + 4 * m];
            }

            float acc[COc][JT];
#pragma unroll
            for (int o = 0; o < COc; ++o)
#pragma unroll
                for (int j = 0; j < JT; ++j)
                    acc[o][j] = bl[o * Sc + s0];

#pragma unroll
            for (int i = 0; i < CIc; ++i) {
                float wa[16], wb[16];
#pragma unroll
                for (int m = 0; m < 4; ++m) {
                    *(f32x4*)&wa[4 * m] = *(const f32x4*)&wl[(0 * CIc + i) * Sc + s0][4 * m];
                    *(f32x4*)&wb[4 * m] = *(const f32x4*)&wl[(1 * CIc + i) * Sc + s0][4 * m];
                }
#pragma unroll
                for (int f = 0; f < NBc; ++f) {
#pragma unroll
                    for (int j = 0; j < JT; ++j) {
                        float xv = (i == 0) ? xa0[j + f + 1] : xa1[j + f + 1];
                        acc[0][j] = fmaf(wa[f], xv, acc[0][j]);
                        acc[1][j] = fmaf(wb[f], xv, acc[1][j]);
                    }
                }
            }

            // fixup: segment-boundary threads, all register indices static
            if (s3 != s0) {
                const int jstart = 499 * s3 - gl0;   // in [1, JT-1]
                const float b0 = bl[0 * Sc + s3];
                const float b1 = bl[1 * Sc + s3];
#pragma unroll
                for (int j = 0; j < JT; ++j) {
                    if (j >= jstart) {
                        float a0 = b0, a1 = b1;
#pragma unroll
                        for (int i = 0; i < CIc; ++i) {
#pragma unroll
                            for (int f = 0; f < NBc; ++f) {
                                float xv = (i == 0) ? xa0[j + f + 1] : xa1[j + f + 1];
                                a0 = fmaf(wl[(0 * CIc + i) * Sc + s3][f], xv, a0);
                                a1 = fmaf(wl[(1 * CIc + i) * Sc + s3][f], xv, a1);
                            }
                        }
                        acc[0][j] = a0;
                        acc[1][j] = a1;
                    }
                }
            }

            // store: 2 nontemporal dwordx4 (NT proven right: r13 plain stores -7.3us)
            float* ob = obase + gl0;
            f32x4 v0 = { acc[0][0], acc[0][1], acc[0][2], acc[0][3] };
            f32x4 v1 = { acc[1][0], acc[1][1], acc[1][2], acc[1][3] };
            __builtin_nontemporal_store(v0, (f32x4*)(ob));
            __builtin_nontemporal_store(v1, (f32x4*)(ob + Lc));
        }
    }
}

extern "C" void kernel_launch(void* const* d_in, const int* in_sizes, int n_in,
                              void* d_out, int out_size, void* d_ws, size_t ws_size,
                              hipStream_t stream) {
    const float* x    = (const float*)d_in[0];
    const float* w    = (const float*)d_in[1];
    const float* bias = (const float*)d_in[2];
    float* out        = (float*)d_out;

    // 512 blocks x 512 threads, 2 blocks/CU: row-pair double-buffered pipeline
    cde_bcr_kernel<<<dim3(NBLK), NTHREADS, 0, stream>>>(x, w, bias, out);
}